// Round 9
// baseline (4445.873 us; speedup 1.0000x reference)
//
#include <hip/hip_runtime.h>
#include <math.h>

typedef unsigned long long ulong_t;

#define Bsz 64
#define Tlen 1024
#define Idim 256
#define Hdim 512
#define Odim 256

#define PB  2              // batches per sync-group
#define NSL 8              // column slices = WGs per group (64 cols each)
#define NG  (Bsz / PB)     // 32 groups -> 256 WGs total

// ---------------------------------------------------------------------------
// Fast-path 8B ops: sc0 = bypass L1, served by the XCD's shared L2.
// Used ONLY as an optimistic fast lane; the agent-scope shadow copy below
// guarantees correctness regardless of WG->XCD placement.
// ---------------------------------------------------------------------------
__device__ __forceinline__ ulong_t load_fast(const ulong_t* p) {
    ulong_t v;
    asm volatile("global_load_dwordx2 %0, %1, off sc0\n\t"
                 "s_waitcnt vmcnt(0)"
                 : "=v"(v) : "v"(p) : "memory");
    return v;
}
__device__ __forceinline__ void store_fast(ulong_t* p, ulong_t v) {
    asm volatile("global_store_dwordx2 %0, %1, off sc0"
                 :: "v"(p), "v"(v) : "memory");
}

// ---------------------------------------------------------------------------
// Kernel A: xproj[b][t][h] = dot(x[b, t0+t, :], Wi[h, :]) + bi[h] + bh[h]
// ---------------------------------------------------------------------------
__global__ __launch_bounds__(256) void xproj_kernel(
        const float* __restrict__ x, const float* __restrict__ Wi,
        const float* __restrict__ bi, const float* __restrict__ bh,
        float* __restrict__ xp, int t0, int CT) {
    __shared__ float As[16][132];
    __shared__ float Bs[16][132];
    const int tid = threadIdx.x;
    const int bm = blockIdx.x, bn = blockIdx.y;
    const int tx = tid & 15, ty = tid >> 4;

    const int f0 = tid, f1 = tid + 256;
    const int ar0 = f0 >> 2, ak0 = (f0 & 3) * 4;
    const int ar1 = f1 >> 2, ak1 = (f1 & 3) * 4;
    const int m0g = bm * 128 + ar0;
    const int m1g = bm * 128 + ar1;
    const int b0 = m0g / CT, tt0 = m0g - b0 * CT;
    const int b1 = m1g / CT, tt1 = m1g - b1 * CT;
    const float* xrow0 = x + ((size_t)b0 * Tlen + t0 + tt0) * Idim;
    const float* xrow1 = x + ((size_t)b1 * Tlen + t0 + tt1) * Idim;
    const float* wrow0 = Wi + (size_t)(bn * 128 + ar0) * Idim;
    const float* wrow1 = Wi + (size_t)(bn * 128 + ar1) * Idim;

    float acc[8][8];
#pragma unroll
    for (int i = 0; i < 8; ++i)
#pragma unroll
        for (int j = 0; j < 8; ++j) acc[i][j] = 0.0f;

    for (int kk = 0; kk < Idim; kk += 16) {
        float4 av0 = *(const float4*)(xrow0 + kk + ak0);
        float4 av1 = *(const float4*)(xrow1 + kk + ak1);
        float4 bv0 = *(const float4*)(wrow0 + kk + ak0);
        float4 bv1 = *(const float4*)(wrow1 + kk + ak1);
        __syncthreads();
        As[ak0 + 0][ar0] = av0.x; As[ak0 + 1][ar0] = av0.y;
        As[ak0 + 2][ar0] = av0.z; As[ak0 + 3][ar0] = av0.w;
        As[ak1 + 0][ar1] = av1.x; As[ak1 + 1][ar1] = av1.y;
        As[ak1 + 2][ar1] = av1.z; As[ak1 + 3][ar1] = av1.w;
        Bs[ak0 + 0][ar0] = bv0.x; Bs[ak0 + 1][ar0] = bv0.y;
        Bs[ak0 + 2][ar0] = bv0.z; Bs[ak0 + 3][ar0] = bv0.w;
        Bs[ak1 + 0][ar1] = bv1.x; Bs[ak1 + 1][ar1] = bv1.y;
        Bs[ak1 + 2][ar1] = bv1.z; Bs[ak1 + 3][ar1] = bv1.w;
        __syncthreads();
#pragma unroll
        for (int k = 0; k < 16; ++k) {
            float4 a0 = *(const float4*)&As[k][tx * 4];
            float4 a1 = *(const float4*)&As[k][64 + tx * 4];
            float4 bq0 = *(const float4*)&Bs[k][ty * 4];
            float4 bq1 = *(const float4*)&Bs[k][64 + ty * 4];
            float a[8] = {a0.x, a0.y, a0.z, a0.w, a1.x, a1.y, a1.z, a1.w};
            float bb[8] = {bq0.x, bq0.y, bq0.z, bq0.w, bq1.x, bq1.y, bq1.z, bq1.w};
#pragma unroll
            for (int i = 0; i < 8; ++i)
#pragma unroll
                for (int j = 0; j < 8; ++j) acc[i][j] += a[i] * bb[j];
        }
    }

    const int n0 = bn * 128;
    float biasv[8];
#pragma unroll
    for (int j = 0; j < 8; ++j) {
        int c = (j < 4) ? (ty * 4 + j) : (64 + ty * 4 + (j - 4));
        biasv[j] = bi[n0 + c] + bh[n0 + c];
    }
#pragma unroll
    for (int i = 0; i < 8; ++i) {
        int r = (i < 4) ? (tx * 4 + i) : (64 + tx * 4 + (i - 4));
        size_t mrow = (size_t)(bm * 128 + r);
        float4 o0 = {acc[i][0] + biasv[0], acc[i][1] + biasv[1],
                     acc[i][2] + biasv[2], acc[i][3] + biasv[3]};
        float4 o1 = {acc[i][4] + biasv[4], acc[i][5] + biasv[5],
                     acc[i][6] + biasv[6], acc[i][7] + biasv[7]};
        *(float4*)(xp + mrow * Hdim + n0 + ty * 4) = o0;
        *(float4*)(xp + mrow * Hdim + n0 + 64 + ty * 4) = o1;
    }
}

// ---------------------------------------------------------------------------
// Kernel B: register-resident-Wh scan; tagged exchange with an L2 fast lane
// and an agent-scope slow lane. Each tagged word: hi32 = step tag, lo32 =
// float h. Producer stores BOTH lanes (no waits). Consumer polls the fast
// word (sc0 -> shared XCD L2 if the group's 8 WGs share an XCD, which the
// swizzle arranges); every 8th iteration it also polls the slow word,
// guaranteeing progress if placement scatters the group across XCDs.
// Correctness never depends on WG->XCD mapping. Double-buffered by parity;
// tag monotonicity makes reuse safe; 0xAA poison can't match a tag.
// ---------------------------------------------------------------------------
__global__ __launch_bounds__(512) void scan_reg(
        const float* __restrict__ xp, const float* __restrict__ Wh,
        ulong_t* __restrict__ hfast, ulong_t* __restrict__ hslow,
        int t0, int CT) {
    const int wg = blockIdx.x;                        // 0..255
    const int g = (wg & 7) + ((wg >> 6) << 3);        // 0..31
    const int n = (wg >> 3) & 7;                      // 0..7
    const int colbase = n * 64;
    const int bbase = g * PB;
    const int tid = threadIdx.x;
    const int ct = tid & 15;                          // col-group 0..15
    const int kg = tid >> 4;                          // k-group 0..31

    // --- Wh fragment into registers (once): w[cc][i] ---
    float4 w[4][4];
#pragma unroll
    for (int cc = 0; cc < 4; ++cc) {
        const float4* src =
            (const float4*)(Wh + (size_t)(colbase + ct * 4 + cc) * Hdim + kg * 16);
#pragma unroll
        for (int i = 0; i < 4; ++i) w[cc][i] = src[i];
    }

    __shared__ float  hs[PB][Hdim];                   // 4 KB
    __shared__ float4 red4[PB][32][17];               // ~17.4 KB

    // --- poll-pair assignment: thread owns 2 adjacent h values ---
    const int pb_ = tid >> 8;                         // batch 0..1
    const int pc  = (tid & 255) * 2;                  // col (even)
    const bool foreign = ((pc >> 6) != n);

    // --- init h_{t0} (prev kernel completed -> slow copy globally visible) ---
    {
        float v0 = 0.f, v1 = 0.f;
        if (t0 != 0) {
            const ulong_t* a =
                hslow + (((size_t)(t0 & 1)) * Bsz + bbase + pb_) * Hdim + pc;
            v0 = __uint_as_float((unsigned)a[0]);
            v1 = __uint_as_float((unsigned)a[1]);
        }
        hs[pb_][pc] = v0;
        hs[pb_][pc + 1] = v1;
    }
    __syncthreads();

    const int fb = tid >> 6;                          // finalize batch (tid<128)
    const int fc = tid & 63;                          // finalize col-in-slice

    // prefetch xp for t=0
    float xv = 0.f;
    if (tid < 128)
        xv = xp[((size_t)(bbase + fb) * CT) * Hdim + colbase + fc];

    for (int t = 0; t < CT; ++t) {
        const int st = t0 + t;
        const int nb = (st + 1) & 1;                  // buffer for h_{st+1}

        // --- partial GEMV: register Wh x LDS-broadcast h ---
        float4 p0 = {0.f, 0.f, 0.f, 0.f};
        float4 p1 = {0.f, 0.f, 0.f, 0.f};
#pragma unroll
        for (int i = 0; i < 4; ++i) {
            float4 h0 = *(const float4*)&hs[0][kg * 16 + i * 4];
            float4 h1 = *(const float4*)&hs[1][kg * 16 + i * 4];
            p0.x += w[0][i].x * h0.x + w[0][i].y * h0.y + w[0][i].z * h0.z + w[0][i].w * h0.w;
            p0.y += w[1][i].x * h0.x + w[1][i].y * h0.y + w[1][i].z * h0.z + w[1][i].w * h0.w;
            p0.z += w[2][i].x * h0.x + w[2][i].y * h0.y + w[2][i].z * h0.z + w[2][i].w * h0.w;
            p0.w += w[3][i].x * h0.x + w[3][i].y * h0.y + w[3][i].z * h0.z + w[3][i].w * h0.w;
            p1.x += w[0][i].x * h1.x + w[0][i].y * h1.y + w[0][i].z * h1.z + w[0][i].w * h1.w;
            p1.y += w[1][i].x * h1.x + w[1][i].y * h1.y + w[1][i].z * h1.z + w[1][i].w * h1.w;
            p1.z += w[2][i].x * h1.x + w[2][i].y * h1.y + w[2][i].z * h1.z + w[2][i].w * h1.w;
            p1.w += w[3][i].x * h1.x + w[3][i].y * h1.y + w[3][i].z * h1.z + w[3][i].w * h1.w;
        }
        red4[0][kg][ct] = p0;
        red4[1][kg][ct] = p1;
        __syncthreads();                              // (A) partials visible

        // prefetch next xp early (overlaps reduce + store + poll)
        float xv_next = 0.f;
        if (tid < 128 && t + 1 < CT)
            xv_next = xp[((size_t)(bbase + fb) * CT + (t + 1)) * Hdim + colbase + fc];

        // --- finalize: reduce 32 k-groups, tanh, dual tagged 8B stores ---
        if (tid < 128) {
            float s = 0.f;
#pragma unroll
            for (int k = 0; k < 32; ++k)
                s += ((const float*)&red4[fb][k][0])[fc];
            float h1v = tanhf(s + xv);
            ulong_t pk = (((ulong_t)(unsigned)(st + 1)) << 32) |
                         (ulong_t)__float_as_uint(h1v);
            const size_t idx =
                ((size_t)nb * Bsz + bbase + fb) * Hdim + colbase + fc;
            store_fast(&hfast[idx], pk);              // L2 fast lane
            __hip_atomic_store(&hslow[idx], pk, __ATOMIC_RELAXED,
                               __HIP_MEMORY_SCOPE_AGENT);  // coherent lane
            hs[fb][colbase + fc] = h1v;               // own slice via LDS
        }
        xv = xv_next;

        if (t + 1 < CT) {
            // --- poll foreign tagged words: fast lane, slow every 8th ---
            if (foreign) {
                const size_t base =
                    ((size_t)nb * Bsz + bbase + pb_) * Hdim + pc;
                ulong_t* af = hfast + base;
                ulong_t* as = hslow + base;
                const unsigned tagexp = (unsigned)(st + 1);
                ulong_t x0 = 0, x1 = 0;
                bool d0 = false, d1 = false;
                int it = 0;
                for (;;) {
                    if (!d0) {
                        ulong_t v = load_fast(af);
                        if ((unsigned)(v >> 32) == tagexp) { x0 = v; d0 = true; }
                    }
                    if (!d1) {
                        ulong_t v = load_fast(af + 1);
                        if ((unsigned)(v >> 32) == tagexp) { x1 = v; d1 = true; }
                    }
                    if (d0 && d1) break;
                    if ((++it & 7) == 0) {            // slow-lane safety net
                        if (!d0) {
                            ulong_t v = __hip_atomic_load(as, __ATOMIC_RELAXED,
                                                          __HIP_MEMORY_SCOPE_AGENT);
                            if ((unsigned)(v >> 32) == tagexp) { x0 = v; d0 = true; }
                        }
                        if (!d1) {
                            ulong_t v = __hip_atomic_load(as + 1, __ATOMIC_RELAXED,
                                                          __HIP_MEMORY_SCOPE_AGENT);
                            if ((unsigned)(v >> 32) == tagexp) { x1 = v; d1 = true; }
                        }
                        if (d0 && d1) break;
                    }
                }
                hs[pb_][pc]     = __uint_as_float((unsigned)x0);
                hs[pb_][pc + 1] = __uint_as_float((unsigned)x1);
            }
            __syncthreads();                          // (D) h_{st+1} ready
        }
    }
}

// ---------------------------------------------------------------------------
// Kernel C: out[b][o] = dot(h_final[b,:], Wo[o,:]) + bo[o]
// Reads the coherent slow buffer, parity (Tlen&1)==0 -> base.
// ---------------------------------------------------------------------------
__global__ __launch_bounds__(256) void out_kernel(
        const ulong_t* __restrict__ hbuf, const float* __restrict__ Wo,
        const float* __restrict__ bo, float* __restrict__ out) {
    __shared__ float hsh[Hdim];
    const int b = blockIdx.x, o = threadIdx.x;
    hsh[o]       = __uint_as_float((unsigned)hbuf[(size_t)b * Hdim + o]);
    hsh[o + 256] = __uint_as_float((unsigned)hbuf[(size_t)b * Hdim + o + 256]);
    __syncthreads();
    const float4* wrow = (const float4*)(Wo + (size_t)o * Hdim);
    const float4* h4 = (const float4*)hsh;
    float4 a4 = {0.0f, 0.0f, 0.0f, 0.0f};
#pragma unroll 4
    for (int i = 0; i < Hdim / 4; ++i) {
        float4 ww = wrow[i];
        float4 hv = h4[i];
        a4.x += ww.x * hv.x;
        a4.y += ww.y * hv.y;
        a4.z += ww.z * hv.z;
        a4.w += ww.w * hv.w;
    }
    out[b * Odim + o] = bo[o] + ((a4.x + a4.y) + (a4.z + a4.w));
}

// ---------------------------------------------------------------------------
extern "C" void kernel_launch(void* const* d_in, const int* in_sizes, int n_in,
                              void* d_out, int out_size, void* d_ws, size_t ws_size,
                              hipStream_t stream) {
    const float* x  = (const float*)d_in[0];
    const float* Wi = (const float*)d_in[1];
    const float* bi = (const float*)d_in[2];
    const float* Wh = (const float*)d_in[3];
    const float* bh = (const float*)d_in[4];
    const float* Wo = (const float*)d_in[5];
    const float* bo = (const float*)d_in[6];
    float* out = (float*)d_out;

    const size_t hbytes = 2ull * Bsz * Hdim * sizeof(ulong_t);  // per lane
    int CT = Tlen;
    while (CT > 2 && (size_t)Bsz * CT * Hdim * sizeof(float) + 2 * hbytes > ws_size)
        CT >>= 1;

    float*   xp    = (float*)d_ws;
    ulong_t* hfast = (ulong_t*)((char*)d_ws + (size_t)Bsz * CT * Hdim * sizeof(float));
    ulong_t* hslow = (ulong_t*)((char*)hfast + hbytes);

    for (int t0 = 0; t0 < Tlen; t0 += CT) {
        xproj_kernel<<<dim3((Bsz * CT) / 128, Hdim / 128), 256, 0, stream>>>(
            x, Wi, bi, bh, xp, t0, CT);
        scan_reg<<<dim3(NG * NSL), 512, 0, stream>>>(xp, Wh, hfast, hslow, t0, CT);
    }
    // final h tag = Tlen (even parity) -> slow buffer 0 = hslow base
    out_kernel<<<dim3(Bsz), 256, 0, stream>>>(hslow, Wo, bo, out);
}

// Round 11
// 2630.632 us; speedup vs baseline: 1.6900x; 1.6900x over previous
//
#include <hip/hip_runtime.h>
#include <math.h>

typedef unsigned long long ulong_t;

#define Bsz 64
#define Tlen 1024
#define Idim 256
#define Hdim 512
#define Odim 256

#define PB  2              // batches per sync-group
#define NSL 8              // column slices = WGs per group (64 cols each)
#define NG  (Bsz / PB)     // 32 groups -> 256 WGs total

// ---------------------------------------------------------------------------
// Kernel A: xproj[b][t][h] = dot(x[b, t0+t, :], Wi[h, :]) + bi[h] + bh[h]
// (unchanged from R3 — ~0.22 ms, not the bottleneck)
// ---------------------------------------------------------------------------
__global__ __launch_bounds__(256) void xproj_kernel(
        const float* __restrict__ x, const float* __restrict__ Wi,
        const float* __restrict__ bi, const float* __restrict__ bh,
        float* __restrict__ xp, int t0, int CT) {
    __shared__ float As[16][132];
    __shared__ float Bs[16][132];
    const int tid = threadIdx.x;
    const int bm = blockIdx.x, bn = blockIdx.y;
    const int tx = tid & 15, ty = tid >> 4;

    const int f0 = tid, f1 = tid + 256;
    const int ar0 = f0 >> 2, ak0 = (f0 & 3) * 4;
    const int ar1 = f1 >> 2, ak1 = (f1 & 3) * 4;
    const int m0g = bm * 128 + ar0;
    const int m1g = bm * 128 + ar1;
    const int b0 = m0g / CT, tt0 = m0g - b0 * CT;
    const int b1 = m1g / CT, tt1 = m1g - b1 * CT;
    const float* xrow0 = x + ((size_t)b0 * Tlen + t0 + tt0) * Idim;
    const float* xrow1 = x + ((size_t)b1 * Tlen + t0 + tt1) * Idim;
    const float* wrow0 = Wi + (size_t)(bn * 128 + ar0) * Idim;
    const float* wrow1 = Wi + (size_t)(bn * 128 + ar1) * Idim;

    float acc[8][8];
#pragma unroll
    for (int i = 0; i < 8; ++i)
#pragma unroll
        for (int j = 0; j < 8; ++j) acc[i][j] = 0.0f;

    for (int kk = 0; kk < Idim; kk += 16) {
        float4 av0 = *(const float4*)(xrow0 + kk + ak0);
        float4 av1 = *(const float4*)(xrow1 + kk + ak1);
        float4 bv0 = *(const float4*)(wrow0 + kk + ak0);
        float4 bv1 = *(const float4*)(wrow1 + kk + ak1);
        __syncthreads();
        As[ak0 + 0][ar0] = av0.x; As[ak0 + 1][ar0] = av0.y;
        As[ak0 + 2][ar0] = av0.z; As[ak0 + 3][ar0] = av0.w;
        As[ak1 + 0][ar1] = av1.x; As[ak1 + 1][ar1] = av1.y;
        As[ak1 + 2][ar1] = av1.z; As[ak1 + 3][ar1] = av1.w;
        Bs[ak0 + 0][ar0] = bv0.x; Bs[ak0 + 1][ar0] = bv0.y;
        Bs[ak0 + 2][ar0] = bv0.z; Bs[ak0 + 3][ar0] = bv0.w;
        Bs[ak1 + 0][ar1] = bv1.x; Bs[ak1 + 1][ar1] = bv1.y;
        Bs[ak1 + 2][ar1] = bv1.z; Bs[ak1 + 3][ar1] = bv1.w;
        __syncthreads();
#pragma unroll
        for (int k = 0; k < 16; ++k) {
            float4 a0 = *(const float4*)&As[k][tx * 4];
            float4 a1 = *(const float4*)&As[k][64 + tx * 4];
            float4 bq0 = *(const float4*)&Bs[k][ty * 4];
            float4 bq1 = *(const float4*)&Bs[k][64 + ty * 4];
            float a[8] = {a0.x, a0.y, a0.z, a0.w, a1.x, a1.y, a1.z, a1.w};
            float bb[8] = {bq0.x, bq0.y, bq0.z, bq0.w, bq1.x, bq1.y, bq1.z, bq1.w};
#pragma unroll
            for (int i = 0; i < 8; ++i)
#pragma unroll
                for (int j = 0; j < 8; ++j) acc[i][j] += a[i] * bb[j];
        }
    }

    const int n0 = bn * 128;
    float biasv[8];
#pragma unroll
    for (int j = 0; j < 8; ++j) {
        int c = (j < 4) ? (ty * 4 + j) : (64 + ty * 4 + (j - 4));
        biasv[j] = bi[n0 + c] + bh[n0 + c];
    }
#pragma unroll
    for (int i = 0; i < 8; ++i) {
        int r = (i < 4) ? (tx * 4 + i) : (64 + tx * 4 + (i - 4));
        size_t mrow = (size_t)(bm * 128 + r);
        float4 o0 = {acc[i][0] + biasv[0], acc[i][1] + biasv[1],
                     acc[i][2] + biasv[2], acc[i][3] + biasv[3]};
        float4 o1 = {acc[i][4] + biasv[4], acc[i][5] + biasv[5],
                     acc[i][6] + biasv[6], acc[i][7] + biasv[7]};
        *(float4*)(xp + mrow * Hdim + n0 + ty * 4) = o0;
        *(float4*)(xp + mrow * Hdim + n0 + 64 + ty * 4) = o1;
    }
}

// ---------------------------------------------------------------------------
// Kernel B: register-resident-Wh scan with SENTINEL-LINE exchange (no RMW).
// Per step, per WG:
//   FMA partials -> red4 -> (A) -> finalize (128 thr): reduce+tanh+4B agent
//   data stores -> finalize waves drain own stores (vmcnt0) + LDS handshake
//   -> tid0 posts sentinel (plain 8B agent store, tag=st+1) into the group's
//   shared 64B sentinel line -> wave0 lanes 0..7 poll that ONE line (one
//   memory transaction/iter) until all 8 tags==st+1 -> (C) -> full h reload
//   (8B/thread agent loads) -> (D).
// Ordering: producer vmcnt(0) before sentinel => data visible when tag seen.
// Monotone tags: poison 0xAA.. never matches; safe across chunk relaunches;
// double-buffered data by step parity (same induction proved in R4).
// ---------------------------------------------------------------------------
__global__ __launch_bounds__(512) void scan_sent(
        const float* __restrict__ xp, const float* __restrict__ Wh,
        float* __restrict__ hdata, ulong_t* __restrict__ sent,
        int t0, int CT) {
    const int wg = blockIdx.x;                        // 0..255
    const int g = (wg & 7) + ((wg >> 6) << 3);        // 0..31
    const int n = (wg >> 3) & 7;                      // 0..7
    const int colbase = n * 64;
    const int bbase = g * PB;
    const int tid = threadIdx.x;
    const int ct = tid & 15;                          // col-group 0..15
    const int kg = tid >> 4;                          // k-group 0..31

    // --- Wh fragment into registers (once): w[cc][i] ---
    float4 w[4][4];
#pragma unroll
    for (int cc = 0; cc < 4; ++cc) {
        const float4* src =
            (const float4*)(Wh + (size_t)(colbase + ct * 4 + cc) * Hdim + kg * 16);
#pragma unroll
        for (int i = 0; i < 4; ++i) w[cc][i] = src[i];
    }

    __shared__ float  hs[PB][Hdim];                   // 4 KB
    __shared__ float4 red4[PB][32][17];               // ~17.4 KB
    __shared__ int    w1flag;

    const int pb_ = tid >> 8;                         // reload batch 0..1
    const int pc  = (tid & 255) * 2;                  // reload col (even)

    // --- init: hs = h_{t0}; w1flag = 0 ---
    if (tid == 0) w1flag = 0;
    {
        float v0 = 0.f, v1 = 0.f;
        if (t0 != 0) {
            const ulong_t* a = (const ulong_t*)
                (hdata + (((size_t)(t0 & 1) * Bsz + bbase + pb_) * Hdim + pc));
            ulong_t v = __hip_atomic_load(a, __ATOMIC_RELAXED,
                                          __HIP_MEMORY_SCOPE_AGENT);
            v0 = __uint_as_float((unsigned)v);
            v1 = __uint_as_float((unsigned)(v >> 32));
        }
        hs[pb_][pc] = v0;
        hs[pb_][pc + 1] = v1;
    }
    __syncthreads();

    const int fb = tid >> 6;                          // finalize batch (tid<128)
    const int fc = tid & 63;                          // finalize col-in-slice
    ulong_t* const sline = sent + (size_t)g * 32;     // group sentinel line

    // prefetch xp for t=0
    float xv = 0.f;
    if (tid < 128)
        xv = xp[((size_t)(bbase + fb) * CT) * Hdim + colbase + fc];

    for (int t = 0; t < CT; ++t) {
        const int st = t0 + t;
        const int nb = (st + 1) & 1;                  // parity of h_{st+1}
        const unsigned tagexp = (unsigned)(st + 1);

        // --- partial GEMV: register Wh x LDS-broadcast h ---
        float4 p0 = {0.f, 0.f, 0.f, 0.f};
        float4 p1 = {0.f, 0.f, 0.f, 0.f};
#pragma unroll
        for (int i = 0; i < 4; ++i) {
            float4 h0 = *(const float4*)&hs[0][kg * 16 + i * 4];
            float4 h1 = *(const float4*)&hs[1][kg * 16 + i * 4];
            p0.x += w[0][i].x * h0.x + w[0][i].y * h0.y + w[0][i].z * h0.z + w[0][i].w * h0.w;
            p0.y += w[1][i].x * h0.x + w[1][i].y * h0.y + w[1][i].z * h0.z + w[1][i].w * h0.w;
            p0.z += w[2][i].x * h0.x + w[2][i].y * h0.y + w[2][i].z * h0.z + w[2][i].w * h0.w;
            p0.w += w[3][i].x * h0.x + w[3][i].y * h0.y + w[3][i].z * h0.z + w[3][i].w * h0.w;
            p1.x += w[0][i].x * h1.x + w[0][i].y * h1.y + w[0][i].z * h1.z + w[0][i].w * h1.w;
            p1.y += w[1][i].x * h1.x + w[1][i].y * h1.y + w[1][i].z * h1.z + w[1][i].w * h1.w;
            p1.z += w[2][i].x * h1.x + w[2][i].y * h1.y + w[2][i].z * h1.z + w[2][i].w * h1.w;
            p1.w += w[3][i].x * h1.x + w[3][i].y * h1.y + w[3][i].z * h1.z + w[3][i].w * h1.w;
        }
        red4[0][kg][ct] = p0;
        red4[1][kg][ct] = p1;
        __syncthreads();                              // (A) partials visible

        // --- finalize: reduce 32 k-groups, tanh, ONE 4B agent data store ---
        if (tid < 128) {
            float s = 0.f;
#pragma unroll
            for (int k = 0; k < 32; ++k)
                s += ((const float*)&red4[fb][k][0])[fc];
            float h1v = tanhf(s + xv);
            __hip_atomic_store(
                &hdata[((size_t)nb * Bsz + bbase + fb) * Hdim + colbase + fc],
                h1v, __ATOMIC_RELAXED, __HIP_MEMORY_SCOPE_AGENT);
        }

        // --- drain own stores, handshake, post sentinel, poll line ---
        if (tid >= 64 && tid < 128) {                 // wave 1 (finalize half)
            asm volatile("s_waitcnt vmcnt(0)" ::: "memory");
            if (tid == 64)
                __hip_atomic_store(&w1flag, (int)tagexp, __ATOMIC_RELAXED,
                                   __HIP_MEMORY_SCOPE_WORKGROUP);
        }
        if (tid < 64) {                               // wave 0
            asm volatile("s_waitcnt vmcnt(0)" ::: "memory");
            while (__hip_atomic_load(&w1flag, __ATOMIC_RELAXED,
                                     __HIP_MEMORY_SCOPE_WORKGROUP) != (int)tagexp) {}
            if (tid == 0)
                __hip_atomic_store(&sline[n], (ulong_t)tagexp, __ATOMIC_RELAXED,
                                   __HIP_MEMORY_SCOPE_AGENT);
            // poll the group's 64B sentinel line: lanes 0..7, one txn/iter
            bool ok = (tid >= 8);
            while (!__all(ok)) {
                if (!ok) {
                    ulong_t v = __hip_atomic_load(&sline[tid], __ATOMIC_RELAXED,
                                                  __HIP_MEMORY_SCOPE_AGENT);
                    ok = ((unsigned)v == tagexp);
                }
            }
        }

        // prefetch next xp (overlaps (C) wait + reload)
        if (tid < 128 && t + 1 < CT)
            xv = xp[((size_t)(bbase + fb) * CT + (t + 1)) * Hdim + colbase + fc];

        __syncthreads();                              // (C) all data visible

        // --- full h_{st+1} reload: 8B agent load per thread ---
        {
            const ulong_t* a = (const ulong_t*)
                (hdata + (((size_t)nb * Bsz + bbase + pb_) * Hdim + pc));
            ulong_t v = __hip_atomic_load(a, __ATOMIC_RELAXED,
                                          __HIP_MEMORY_SCOPE_AGENT);
            hs[pb_][pc]     = __uint_as_float((unsigned)v);
            hs[pb_][pc + 1] = __uint_as_float((unsigned)(v >> 32));
        }
        __syncthreads();                              // (D) hs = h_{st+1}
    }
}

// ---------------------------------------------------------------------------
// Kernel C: out[b][o] = dot(h_final[b,:], Wo[o,:]) + bo[o]
// h_final parity (Tlen & 1)==0 -> hdata buffer 0.
// ---------------------------------------------------------------------------
__global__ __launch_bounds__(256) void out_kernel(
        const float* __restrict__ hbuf, const float* __restrict__ Wo,
        const float* __restrict__ bo, float* __restrict__ out) {
    __shared__ float hsh[Hdim];
    const int b = blockIdx.x, o = threadIdx.x;
    hsh[o] = hbuf[(size_t)b * Hdim + o];
    hsh[o + 256] = hbuf[(size_t)b * Hdim + o + 256];
    __syncthreads();
    const float4* wrow = (const float4*)(Wo + (size_t)o * Hdim);
    const float4* h4 = (const float4*)hsh;
    float4 a4 = {0.0f, 0.0f, 0.0f, 0.0f};
#pragma unroll 4
    for (int i = 0; i < Hdim / 4; ++i) {
        float4 ww = wrow[i];
        float4 hv = h4[i];
        a4.x += ww.x * hv.x;
        a4.y += ww.y * hv.y;
        a4.z += ww.z * hv.z;
        a4.w += ww.w * hv.w;
    }
    out[b * Odim + o] = bo[o] + ((a4.x + a4.y) + (a4.z + a4.w));
}

// ---------------------------------------------------------------------------
extern "C" void kernel_launch(void* const* d_in, const int* in_sizes, int n_in,
                              void* d_out, int out_size, void* d_ws, size_t ws_size,
                              hipStream_t stream) {
    const float* x  = (const float*)d_in[0];
    const float* Wi = (const float*)d_in[1];
    const float* bi = (const float*)d_in[2];
    const float* Wh = (const float*)d_in[3];
    const float* bh = (const float*)d_in[4];
    const float* Wo = (const float*)d_in[5];
    const float* bo = (const float*)d_in[6];
    float* out = (float*)d_out;

    const size_t hbytes = 2ull * Bsz * Hdim * sizeof(float);   // data dbuf
    const size_t sbytes = (size_t)NG * 32 * sizeof(ulong_t);   // sentinel lines
    int CT = Tlen;
    while (CT > 2 &&
           (size_t)Bsz * CT * Hdim * sizeof(float) + hbytes + sbytes > ws_size)
        CT >>= 1;

    float*   xp    = (float*)d_ws;
    float*   hdata = (float*)((char*)d_ws + (size_t)Bsz * CT * Hdim * sizeof(float));
    ulong_t* sent  = (ulong_t*)((char*)hdata + hbytes);

    for (int t0 = 0; t0 < Tlen; t0 += CT) {
        xproj_kernel<<<dim3((Bsz * CT) / 128, Hdim / 128), 256, 0, stream>>>(
            x, Wi, bi, bh, xp, t0, CT);
        scan_sent<<<dim3(NG * NSL), 512, 0, stream>>>(xp, Wh, hdata, sent, t0, CT);
    }
    // final h parity (Tlen & 1)==0 -> hdata buffer 0
    out_kernel<<<dim3(Bsz), 256, 0, stream>>>(hdata, Wo, bo, out);
}

// Round 13
// 2132.096 us; speedup vs baseline: 2.0852x; 1.2338x over previous
//
#include <hip/hip_runtime.h>
#include <math.h>

typedef unsigned long long ulong_t;
typedef unsigned int u32x4 __attribute__((ext_vector_type(4)));

#define Bsz 64
#define Tlen 1024
#define Idim 256
#define Hdim 512
#define Odim 256

#define PB  2              // batches per sync-group
#define NSL 8              // column slices = WGs per group (64 cols each)
#define NG  (Bsz / PB)     // 32 groups -> 256 WGs total

// ---------------------------------------------------------------------------
// 16B agent-visible load of two adjacent tagged words (data0,tag0,data1,tag1).
// sc0 sc1 = bypass L1/L2, served at the device coherence point (same path the
// proven __hip_atomic_load(AGENT) polls used in R4).
// ---------------------------------------------------------------------------
__device__ __forceinline__ u32x4 load2_agent(const ulong_t* p) {
    u32x4 v;
    asm volatile("global_load_dwordx4 %0, %1, off sc0 sc1\n\t"
                 "s_waitcnt vmcnt(0)"
                 : "=v"(v) : "v"(p) : "memory");
    return v;
}

// ---------------------------------------------------------------------------
// Kernel A: xproj[b][t][h] = dot(x[b, t0+t, :], Wi[h, :]) + bi[h] + bh[h]
// (unchanged — ~0.22 ms, not the bottleneck)
// ---------------------------------------------------------------------------
__global__ __launch_bounds__(256) void xproj_kernel(
        const float* __restrict__ x, const float* __restrict__ Wi,
        const float* __restrict__ bi, const float* __restrict__ bh,
        float* __restrict__ xp, int t0, int CT) {
    __shared__ float As[16][132];
    __shared__ float Bs[16][132];
    const int tid = threadIdx.x;
    const int bm = blockIdx.x, bn = blockIdx.y;
    const int tx = tid & 15, ty = tid >> 4;

    const int f0 = tid, f1 = tid + 256;
    const int ar0 = f0 >> 2, ak0 = (f0 & 3) * 4;
    const int ar1 = f1 >> 2, ak1 = (f1 & 3) * 4;
    const int m0g = bm * 128 + ar0;
    const int m1g = bm * 128 + ar1;
    const int b0 = m0g / CT, tt0 = m0g - b0 * CT;
    const int b1 = m1g / CT, tt1 = m1g - b1 * CT;
    const float* xrow0 = x + ((size_t)b0 * Tlen + t0 + tt0) * Idim;
    const float* xrow1 = x + ((size_t)b1 * Tlen + t0 + tt1) * Idim;
    const float* wrow0 = Wi + (size_t)(bn * 128 + ar0) * Idim;
    const float* wrow1 = Wi + (size_t)(bn * 128 + ar1) * Idim;

    float acc[8][8];
#pragma unroll
    for (int i = 0; i < 8; ++i)
#pragma unroll
        for (int j = 0; j < 8; ++j) acc[i][j] = 0.0f;

    for (int kk = 0; kk < Idim; kk += 16) {
        float4 av0 = *(const float4*)(xrow0 + kk + ak0);
        float4 av1 = *(const float4*)(xrow1 + kk + ak1);
        float4 bv0 = *(const float4*)(wrow0 + kk + ak0);
        float4 bv1 = *(const float4*)(wrow1 + kk + ak1);
        __syncthreads();
        As[ak0 + 0][ar0] = av0.x; As[ak0 + 1][ar0] = av0.y;
        As[ak0 + 2][ar0] = av0.z; As[ak0 + 3][ar0] = av0.w;
        As[ak1 + 0][ar1] = av1.x; As[ak1 + 1][ar1] = av1.y;
        As[ak1 + 2][ar1] = av1.z; As[ak1 + 3][ar1] = av1.w;
        Bs[ak0 + 0][ar0] = bv0.x; Bs[ak0 + 1][ar0] = bv0.y;
        Bs[ak0 + 2][ar0] = bv0.z; Bs[ak0 + 3][ar0] = bv0.w;
        Bs[ak1 + 0][ar1] = bv1.x; Bs[ak1 + 1][ar1] = bv1.y;
        Bs[ak1 + 2][ar1] = bv1.z; Bs[ak1 + 3][ar1] = bv1.w;
        __syncthreads();
#pragma unroll
        for (int k = 0; k < 16; ++k) {
            float4 a0 = *(const float4*)&As[k][tx * 4];
            float4 a1 = *(const float4*)&As[k][64 + tx * 4];
            float4 bq0 = *(const float4*)&Bs[k][ty * 4];
            float4 bq1 = *(const float4*)&Bs[k][64 + ty * 4];
            float a[8] = {a0.x, a0.y, a0.z, a0.w, a1.x, a1.y, a1.z, a1.w};
            float bb[8] = {bq0.x, bq0.y, bq0.z, bq0.w, bq1.x, bq1.y, bq1.z, bq1.w};
#pragma unroll
            for (int i = 0; i < 8; ++i)
#pragma unroll
                for (int j = 0; j < 8; ++j) acc[i][j] += a[i] * bb[j];
        }
    }

    const int n0 = bn * 128;
    float biasv[8];
#pragma unroll
    for (int j = 0; j < 8; ++j) {
        int c = (j < 4) ? (ty * 4 + j) : (64 + ty * 4 + (j - 4));
        biasv[j] = bi[n0 + c] + bh[n0 + c];
    }
#pragma unroll
    for (int i = 0; i < 8; ++i) {
        int r = (i < 4) ? (tx * 4 + i) : (64 + tx * 4 + (i - 4));
        size_t mrow = (size_t)(bm * 128 + r);
        float4 o0 = {acc[i][0] + biasv[0], acc[i][1] + biasv[1],
                     acc[i][2] + biasv[2], acc[i][3] + biasv[3]};
        float4 o1 = {acc[i][4] + biasv[4], acc[i][5] + biasv[5],
                     acc[i][6] + biasv[6], acc[i][7] + biasv[7]};
        *(float4*)(xp + mrow * Hdim + n0 + ty * 4) = o0;
        *(float4*)(xp + mrow * Hdim + n0 + 64 + ty * 4) = o1;
    }
}

// ---------------------------------------------------------------------------
// Kernel B: register-resident-Wh scan; TAGGED detect=deliver exchange with
// PHASE-CORRECTED first poll. hglob = ulong[2][Bsz][Hdim]: hi32 = step tag,
// lo32 = h bits. Producers: reduce+tanh+ONE 8B tagged agent store (no drain,
// no flags, no extra barrier). Consumers: s_sleep (~0.3us, so the first poll
// arrives at the MALL just AFTER stores land), then one 16B paired probe;
// stragglers re-polled with 8B agent loads. Double-buffered by parity; tag
// monotonicity => 0xAA poison never matches and buffer reuse is safe (a
// producer at step s+2 has consumed every peer's s+1 output).
// ---------------------------------------------------------------------------
__global__ __launch_bounds__(512) void scan_reg(
        const float* __restrict__ xp, const float* __restrict__ Wh,
        ulong_t* __restrict__ hglob, int t0, int CT) {
    const int wg = blockIdx.x;                        // 0..255
    const int g = (wg & 7) + ((wg >> 6) << 3);        // 0..31
    const int n = (wg >> 3) & 7;                      // 0..7
    const int colbase = n * 64;
    const int bbase = g * PB;
    const int tid = threadIdx.x;
    const int ct = tid & 15;                          // col-group 0..15
    const int kg = tid >> 4;                          // k-group 0..31

    // --- Wh fragment into registers (once): w[cc][i] ---
    float4 w[4][4];
#pragma unroll
    for (int cc = 0; cc < 4; ++cc) {
        const float4* src =
            (const float4*)(Wh + (size_t)(colbase + ct * 4 + cc) * Hdim + kg * 16);
#pragma unroll
        for (int i = 0; i < 4; ++i) w[cc][i] = src[i];
    }

    __shared__ float  hs[PB][Hdim];                   // 4 KB
    __shared__ float4 red4[PB][32][17];               // ~17.4 KB

    // --- poll-pair assignment: thread owns 2 adjacent h words (16B aligned) ---
    const int pb_ = tid >> 8;                         // batch 0..1
    const int pc  = (tid & 255) * 2;                  // col (even)
    const bool foreign = ((pc >> 6) != n);

    // --- init h_{t0} (prev chunk kernel completed -> plain visibility) ---
    {
        float v0 = 0.f, v1 = 0.f;
        if (t0 != 0) {
            const ulong_t* a =
                hglob + (((size_t)(t0 & 1)) * Bsz + bbase + pb_) * Hdim + pc;
            v0 = __uint_as_float((unsigned)a[0]);
            v1 = __uint_as_float((unsigned)a[1]);
        }
        hs[pb_][pc] = v0;
        hs[pb_][pc + 1] = v1;
    }
    __syncthreads();

    const int fb = tid >> 6;                          // finalize batch (tid<128)
    const int fc = tid & 63;                          // finalize col-in-slice

    // prefetch xp for t=0
    float xv = 0.f;
    if (tid < 128)
        xv = xp[((size_t)(bbase + fb) * CT) * Hdim + colbase + fc];

    for (int t = 0; t < CT; ++t) {
        const int st = t0 + t;
        const int nb = (st + 1) & 1;                  // buffer for h_{st+1}

        // --- partial GEMV: register Wh x LDS-broadcast h ---
        float4 p0 = {0.f, 0.f, 0.f, 0.f};
        float4 p1 = {0.f, 0.f, 0.f, 0.f};
#pragma unroll
        for (int i = 0; i < 4; ++i) {
            float4 h0 = *(const float4*)&hs[0][kg * 16 + i * 4];
            float4 h1 = *(const float4*)&hs[1][kg * 16 + i * 4];
            p0.x += w[0][i].x * h0.x + w[0][i].y * h0.y + w[0][i].z * h0.z + w[0][i].w * h0.w;
            p0.y += w[1][i].x * h0.x + w[1][i].y * h0.y + w[1][i].z * h0.z + w[1][i].w * h0.w;
            p0.z += w[2][i].x * h0.x + w[2][i].y * h0.y + w[2][i].z * h0.z + w[2][i].w * h0.w;
            p0.w += w[3][i].x * h0.x + w[3][i].y * h0.y + w[3][i].z * h0.z + w[3][i].w * h0.w;
            p1.x += w[0][i].x * h1.x + w[0][i].y * h1.y + w[0][i].z * h1.z + w[0][i].w * h1.w;
            p1.y += w[1][i].x * h1.x + w[1][i].y * h1.y + w[1][i].z * h1.z + w[1][i].w * h1.w;
            p1.z += w[2][i].x * h1.x + w[2][i].y * h1.y + w[2][i].z * h1.z + w[2][i].w * h1.w;
            p1.w += w[3][i].x * h1.x + w[3][i].y * h1.y + w[3][i].z * h1.z + w[3][i].w * h1.w;
        }
        red4[0][kg][ct] = p0;
        red4[1][kg][ct] = p1;
        __syncthreads();                              // (A) partials visible

        // prefetch next xp early (overlaps reduce + store + poll)
        float xv_next = 0.f;
        if (tid < 128 && t + 1 < CT)
            xv_next = xp[((size_t)(bbase + fb) * CT + (t + 1)) * Hdim + colbase + fc];

        // --- finalize: reduce 32 k-groups, tanh, ONE tagged 8B store ---
        if (tid < 128) {
            float s = 0.f;
#pragma unroll
            for (int k = 0; k < 32; ++k)
                s += ((const float*)&red4[fb][k][0])[fc];
            float h1v = tanhf(s + xv);
            ulong_t pk = (((ulong_t)(unsigned)(st + 1)) << 32) |
                         (ulong_t)__float_as_uint(h1v);
            __hip_atomic_store(
                &hglob[((size_t)nb * Bsz + bbase + fb) * Hdim + colbase + fc],
                pk, __ATOMIC_RELAXED, __HIP_MEMORY_SCOPE_AGENT);
            hs[fb][colbase + fc] = h1v;               // own slice via LDS
        }
        xv = xv_next;

        if (t + 1 < CT) {
            if (foreign) {
                const ulong_t* a =
                    hglob + ((size_t)nb * Bsz + bbase + pb_) * Hdim + pc;
                const unsigned tagexp = (unsigned)(st + 1);
                // phase-corrected first probe: sleep so the poll arrives at
                // the coherence point just after producer stores land.
                if (tid < 128) __builtin_amdgcn_s_sleep(4);   // ~0.11us
                else           __builtin_amdgcn_s_sleep(12);  // ~0.32us
                u32x4 v = load2_agent(a);   // [data0,tag0,data1,tag1]
                float f0 = __uint_as_float(v.x);
                float f1 = __uint_as_float(v.z);
                bool d0 = (v.y == tagexp);
                bool d1 = (v.w == tagexp);
                while (!(d0 && d1)) {       // straggler path: 8B re-polls
                    if (!d0) {
                        ulong_t q = __hip_atomic_load(a, __ATOMIC_RELAXED,
                                                      __HIP_MEMORY_SCOPE_AGENT);
                        if ((unsigned)(q >> 32) == tagexp) {
                            f0 = __uint_as_float((unsigned)q); d0 = true;
                        }
                    }
                    if (!d1) {
                        ulong_t q = __hip_atomic_load(a + 1, __ATOMIC_RELAXED,
                                                      __HIP_MEMORY_SCOPE_AGENT);
                        if ((unsigned)(q >> 32) == tagexp) {
                            f1 = __uint_as_float((unsigned)q); d1 = true;
                        }
                    }
                }
                hs[pb_][pc]     = f0;
                hs[pb_][pc + 1] = f1;
            }
            __syncthreads();                          // (D) h_{st+1} ready
        }
    }
}

// ---------------------------------------------------------------------------
// Kernel C: out[b][o] = dot(h_final[b,:], Wo[o,:]) + bo[o]
// h_final: tagged buffer parity (Tlen&1)==0 -> hglob base; lo 32b = value.
// ---------------------------------------------------------------------------
__global__ __launch_bounds__(256) void out_kernel(
        const ulong_t* __restrict__ hbuf, const float* __restrict__ Wo,
        const float* __restrict__ bo, float* __restrict__ out) {
    __shared__ float hsh[Hdim];
    const int b = blockIdx.x, o = threadIdx.x;
    hsh[o]       = __uint_as_float((unsigned)hbuf[(size_t)b * Hdim + o]);
    hsh[o + 256] = __uint_as_float((unsigned)hbuf[(size_t)b * Hdim + o + 256]);
    __syncthreads();
    const float4* wrow = (const float4*)(Wo + (size_t)o * Hdim);
    const float4* h4 = (const float4*)hsh;
    float4 a4 = {0.0f, 0.0f, 0.0f, 0.0f};
#pragma unroll 4
    for (int i = 0; i < Hdim / 4; ++i) {
        float4 ww = wrow[i];
        float4 hv = h4[i];
        a4.x += ww.x * hv.x;
        a4.y += ww.y * hv.y;
        a4.z += ww.z * hv.z;
        a4.w += ww.w * hv.w;
    }
    out[b * Odim + o] = bo[o] + ((a4.x + a4.y) + (a4.z + a4.w));
}

// ---------------------------------------------------------------------------
extern "C" void kernel_launch(void* const* d_in, const int* in_sizes, int n_in,
                              void* d_out, int out_size, void* d_ws, size_t ws_size,
                              hipStream_t stream) {
    const float* x  = (const float*)d_in[0];
    const float* Wi = (const float*)d_in[1];
    const float* bi = (const float*)d_in[2];
    const float* Wh = (const float*)d_in[3];
    const float* bh = (const float*)d_in[4];
    const float* Wo = (const float*)d_in[5];
    const float* bo = (const float*)d_in[6];
    float* out = (float*)d_out;

    const size_t hbytes = 2ull * Bsz * Hdim * sizeof(ulong_t);  // tagged dbuf
    int CT = Tlen;
    while (CT > 2 && (size_t)Bsz * CT * Hdim * sizeof(float) + hbytes > ws_size)
        CT >>= 1;

    float*   xp    = (float*)d_ws;
    ulong_t* hglob = (ulong_t*)((char*)d_ws + (size_t)Bsz * CT * Hdim * sizeof(float));

    for (int t0 = 0; t0 < Tlen; t0 += CT) {
        xproj_kernel<<<dim3((Bsz * CT) / 128, Hdim / 128), 256, 0, stream>>>(
            x, Wi, bi, bh, xp, t0, CT);
        scan_reg<<<dim3(NG * NSL), 512, 0, stream>>>(xp, Wh, hglob, t0, CT);
    }
    // final h tag = Tlen (even parity) -> buffer 0 = hglob base
    out_kernel<<<dim3(Bsz), 256, 0, stream>>>(hglob, Wo, bo, out);
}

// Round 15
// 2033.517 us; speedup vs baseline: 2.1863x; 1.0485x over previous
//
#include <hip/hip_runtime.h>
#include <math.h>

typedef unsigned long long ulong_t;
typedef unsigned int u32x4 __attribute__((ext_vector_type(4)));

#define Bsz 64
#define Tlen 1024
#define Idim 256
#define Hdim 512
#define Odim 256

#define PB  2              // batches per sync-group
#define NSL 8              // column slices = WGs per group (64 cols each)
#define NG  (Bsz / PB)     // 32 groups -> 256 WGs total

// ---------------------------------------------------------------------------
// 16B agent-visible load of two adjacent tagged words (data0,tag0,data1,tag1).
// ---------------------------------------------------------------------------
__device__ __forceinline__ u32x4 load2_agent(const ulong_t* p) {
    u32x4 v;
    asm volatile("global_load_dwordx4 %0, %1, off sc0 sc1\n\t"
                 "s_waitcnt vmcnt(0)"
                 : "=v"(v) : "v"(p) : "memory");
    return v;
}

// ---------------------------------------------------------------------------
// FUSED scan: h_{t+1} = tanh(Wi x_t + bi + bh + Wh h_t), T=1024 steps, one
// launch. WG (g,n): batches g*2..g*2+1, cols n*64..n*64+63.
//   - Wh slice [64x512] in VGPRs (64/thread), Wi slice [64x256] in VGPRs
//     (32/thread). Thread (ct,kg): cols ct*4..+3; Wh k's kg*16..+15,
//     Wi k's kg*8..+7.
//   - x rows (2KB/step) prefetched into regs during the poll phase, staged
//     in double-buffered LDS; Wi partials accumulate into the same
//     reduction tree as Wh partials; biases fold into finalize.
//   - Exchange: R13's proven tagged detect=deliver protocol, phase-corrected
//     first poll (s_sleep), 16B paired probes, 8B straggler re-polls.
//     hglob = ulong[2][Bsz][Hdim]: hi32 = step tag, lo32 = h bits.
//     Double-buffered by parity; tag monotonicity => 0xAA poison never
//     matches; buffer reuse safe (producer at step t+2 implies all peers
//     finished t+1, which implies h_{t+1} fully consumed).
// ---------------------------------------------------------------------------
__global__ __launch_bounds__(512) void scan_fused(
        const float* __restrict__ x, const float* __restrict__ Wi,
        const float* __restrict__ bi, const float* __restrict__ Wh,
        const float* __restrict__ bh, ulong_t* __restrict__ hglob) {
    const int wg = blockIdx.x;                        // 0..255
    const int g = (wg & 7) + ((wg >> 6) << 3);        // 0..31
    const int n = (wg >> 3) & 7;                      // 0..7
    const int colbase = n * 64;
    const int bbase = g * PB;
    const int tid = threadIdx.x;
    const int ct = tid & 15;                          // col-group 0..15
    const int kg = tid >> 4;                          // k-group 0..31

    // --- Wh fragment into registers: w[cc][i] (16 k's) ---
    float4 w[4][4];
#pragma unroll
    for (int cc = 0; cc < 4; ++cc) {
        const float4* src =
            (const float4*)(Wh + (size_t)(colbase + ct * 4 + cc) * Hdim + kg * 16);
#pragma unroll
        for (int i = 0; i < 4; ++i) w[cc][i] = src[i];
    }
    // --- Wi fragment into registers: wi[cc][i] (8 k's) ---
    float4 wi[4][2];
#pragma unroll
    for (int cc = 0; cc < 4; ++cc) {
        const float4* src =
            (const float4*)(Wi + (size_t)(colbase + ct * 4 + cc) * Idim + kg * 8);
#pragma unroll
        for (int i = 0; i < 2; ++i) wi[cc][i] = src[i];
    }

    __shared__ float  hs[PB][Hdim];                   // 4 KB
    __shared__ float4 red4[PB][32][17];               // ~17.4 KB
    __shared__ float  xs[2][PB][Idim];                // 4 KB, dbuf x rows

    // --- poll-pair assignment: thread owns 2 adjacent h words ---
    const int pb_ = tid >> 8;                         // batch 0..1
    const int pc  = (tid & 255) * 2;                  // col (even)
    const bool foreign = ((pc >> 6) != n);

    // --- x loader assignment: 1 float/thread covers 2x256 ---
    const int xb = tid >> 8, xk = tid & 255;
    const float* xrow = x + ((size_t)(bbase + xb) * Tlen) * Idim + xk;

    // --- init: h_0 = 0; xs[0] = x[:,0,:] ---
    hs[pb_][pc] = 0.f;
    hs[pb_][pc + 1] = 0.f;
    xs[0][xb][xk] = xrow[0];

    const int fb = tid >> 6;                          // finalize batch (tid<128)
    const int fc = tid & 63;                          // finalize col-in-slice
    float biasv = 0.f;
    if (tid < 128) biasv = bi[colbase + fc] + bh[colbase + fc];
    __syncthreads();

    for (int t = 0; t < Tlen; ++t) {
        const int par = t & 1;
        const int nb = (t + 1) & 1;                   // buffer for h_{t+1}

        // --- partial GEMV: (Wh x LDS h) + (Wi x LDS x_t), both batches ---
        float4 p0 = {0.f, 0.f, 0.f, 0.f};
        float4 p1 = {0.f, 0.f, 0.f, 0.f};
#pragma unroll
        for (int i = 0; i < 4; ++i) {
            float4 h0 = *(const float4*)&hs[0][kg * 16 + i * 4];
            float4 h1 = *(const float4*)&hs[1][kg * 16 + i * 4];
            p0.x += w[0][i].x * h0.x + w[0][i].y * h0.y + w[0][i].z * h0.z + w[0][i].w * h0.w;
            p0.y += w[1][i].x * h0.x + w[1][i].y * h0.y + w[1][i].z * h0.z + w[1][i].w * h0.w;
            p0.z += w[2][i].x * h0.x + w[2][i].y * h0.y + w[2][i].z * h0.z + w[2][i].w * h0.w;
            p0.w += w[3][i].x * h0.x + w[3][i].y * h0.y + w[3][i].z * h0.z + w[3][i].w * h0.w;
            p1.x += w[0][i].x * h1.x + w[0][i].y * h1.y + w[0][i].z * h1.z + w[0][i].w * h1.w;
            p1.y += w[1][i].x * h1.x + w[1][i].y * h1.y + w[1][i].z * h1.z + w[1][i].w * h1.w;
            p1.z += w[2][i].x * h1.x + w[2][i].y * h1.y + w[2][i].z * h1.z + w[2][i].w * h1.w;
            p1.w += w[3][i].x * h1.x + w[3][i].y * h1.y + w[3][i].z * h1.z + w[3][i].w * h1.w;
        }
#pragma unroll
        for (int i = 0; i < 2; ++i) {
            float4 x0 = *(const float4*)&xs[par][0][kg * 8 + i * 4];
            float4 x1 = *(const float4*)&xs[par][1][kg * 8 + i * 4];
            p0.x += wi[0][i].x * x0.x + wi[0][i].y * x0.y + wi[0][i].z * x0.z + wi[0][i].w * x0.w;
            p0.y += wi[1][i].x * x0.x + wi[1][i].y * x0.y + wi[1][i].z * x0.z + wi[1][i].w * x0.w;
            p0.z += wi[2][i].x * x0.x + wi[2][i].y * x0.y + wi[2][i].z * x0.z + wi[2][i].w * x0.w;
            p0.w += wi[3][i].x * x0.x + wi[3][i].y * x0.y + wi[3][i].z * x0.z + wi[3][i].w * x0.w;
            p1.x += wi[0][i].x * x1.x + wi[0][i].y * x1.y + wi[0][i].z * x1.z + wi[0][i].w * x1.w;
            p1.y += wi[1][i].x * x1.x + wi[1][i].y * x1.y + wi[1][i].z * x1.z + wi[1][i].w * x1.w;
            p1.z += wi[2][i].x * x1.x + wi[2][i].y * x1.y + wi[2][i].z * x1.z + wi[2][i].w * x1.w;
            p1.w += wi[3][i].x * x1.x + wi[3][i].y * x1.y + wi[3][i].z * x1.z + wi[3][i].w * x1.w;
        }
        red4[0][kg][ct] = p0;
        red4[1][kg][ct] = p1;
        __syncthreads();                              // (A) partials visible

        // --- finalize: reduce 32 k-groups, +bias, tanh, tagged 8B store ---
        if (tid < 128) {
            float s = biasv;
#pragma unroll
            for (int k = 0; k < 32; ++k)
                s += ((const float*)&red4[fb][k][0])[fc];
            float h1v = tanhf(s);
            ulong_t pk = (((ulong_t)(unsigned)(t + 1)) << 32) |
                         (ulong_t)__float_as_uint(h1v);
            __hip_atomic_store(
                &hglob[((size_t)nb * Bsz + bbase + fb) * Hdim + colbase + fc],
                pk, __ATOMIC_RELAXED, __HIP_MEMORY_SCOPE_AGENT);
            hs[fb][colbase + fc] = h1v;               // own slice via LDS
        }

        if (t + 1 < Tlen) {
            // issue x prefetch for t+1 (lands under the poll below)
            float xr = xrow[(size_t)(t + 1) * Idim];

            if (foreign) {
                const ulong_t* a =
                    hglob + ((size_t)nb * Bsz + bbase + pb_) * Hdim + pc;
                const unsigned tagexp = (unsigned)(t + 1);
                // phase-corrected first probe
                if (tid < 128) __builtin_amdgcn_s_sleep(4);   // ~0.11us
                else           __builtin_amdgcn_s_sleep(12);  // ~0.32us
                u32x4 v = load2_agent(a);   // [data0,tag0,data1,tag1]
                float f0 = __uint_as_float(v.x);
                float f1 = __uint_as_float(v.z);
                bool d0 = (v.y == tagexp);
                bool d1 = (v.w == tagexp);
                while (!(d0 && d1)) {       // straggler path: 8B re-polls
                    if (!d0) {
                        ulong_t q = __hip_atomic_load(a, __ATOMIC_RELAXED,
                                                      __HIP_MEMORY_SCOPE_AGENT);
                        if ((unsigned)(q >> 32) == tagexp) {
                            f0 = __uint_as_float((unsigned)q); d0 = true;
                        }
                    }
                    if (!d1) {
                        ulong_t q = __hip_atomic_load(a + 1, __ATOMIC_RELAXED,
                                                      __HIP_MEMORY_SCOPE_AGENT);
                        if ((unsigned)(q >> 32) == tagexp) {
                            f1 = __uint_as_float((unsigned)q); d1 = true;
                        }
                    }
                }
                hs[pb_][pc]     = f0;
                hs[pb_][pc + 1] = f1;
            }
            xs[nb][xb][xk] = xr;                      // stage x_{t+1}
            __syncthreads();                          // (D) h_{t+1}, x_{t+1} ready
        }
    }
}

// ---------------------------------------------------------------------------
// Kernel C: out[b][o] = dot(h_final[b,:], Wo[o,:]) + bo[o]
// h_final: tag=Tlen (even parity) -> hglob buffer 0; lo 32b = value.
// ---------------------------------------------------------------------------
__global__ __launch_bounds__(256) void out_kernel(
        const ulong_t* __restrict__ hbuf, const float* __restrict__ Wo,
        const float* __restrict__ bo, float* __restrict__ out) {
    __shared__ float hsh[Hdim];
    const int b = blockIdx.x, o = threadIdx.x;
    hsh[o]       = __uint_as_float((unsigned)hbuf[(size_t)b * Hdim + o]);
    hsh[o + 256] = __uint_as_float((unsigned)hbuf[(size_t)b * Hdim + o + 256]);
    __syncthreads();
    const float4* wrow = (const float4*)(Wo + (size_t)o * Hdim);
    const float4* h4 = (const float4*)hsh;
    float4 a4 = {0.0f, 0.0f, 0.0f, 0.0f};
#pragma unroll 4
    for (int i = 0; i < Hdim / 4; ++i) {
        float4 ww = wrow[i];
        float4 hv = h4[i];
        a4.x += ww.x * hv.x;
        a4.y += ww.y * hv.y;
        a4.z += ww.z * hv.z;
        a4.w += ww.w * hv.w;
    }
    out[b * Odim + o] = bo[o] + ((a4.x + a4.y) + (a4.z + a4.w));
}

// ---------------------------------------------------------------------------
extern "C" void kernel_launch(void* const* d_in, const int* in_sizes, int n_in,
                              void* d_out, int out_size, void* d_ws, size_t ws_size,
                              hipStream_t stream) {
    const float* x  = (const float*)d_in[0];
    const float* Wi = (const float*)d_in[1];
    const float* bi = (const float*)d_in[2];
    const float* Wh = (const float*)d_in[3];
    const float* bh = (const float*)d_in[4];
    const float* Wo = (const float*)d_in[5];
    const float* bo = (const float*)d_in[6];
    float* out = (float*)d_out;

    ulong_t* hglob = (ulong_t*)d_ws;   // 2 x 64 x 512 x 8B = 512 KB

    scan_fused<<<dim3(NG * NSL), 512, 0, stream>>>(x, Wi, bi, Wh, bh, hglob);
    // final h tag = Tlen (even parity) -> buffer 0 = hglob base
    out_kernel<<<dim3(Bsz), 256, 0, stream>>>(hglob, Wo, bo, out);
}